// Round 7
// baseline (138.365 us; speedup 1.0000x reference)
//
#include <hip/hip_runtime.h>
#include <math.h>

#define Bb 2
#define Nn 2048
#define Hh 256
#define NH 8
#define NEDGE 65536
#define LN_EPS 1e-5f
#define MW 64          // mask words per row = N/32
#define LDA2 72

typedef __bf16 bf16_t;
typedef bf16_t bf16x8 __attribute__((ext_vector_type(8)));
typedef bf16_t bf16x4 __attribute__((ext_vector_type(4)));
typedef float f32x4 __attribute__((ext_vector_type(4)));

// ======================= K1: cvt to bf16 + mask zero ========================
__global__ __launch_bounds__(256) void cvt_zero_kernel(
    const float* __restrict__ s0, const float* __restrict__ s1, const float* __restrict__ s2,
    const float* __restrict__ s3, const float* __restrict__ s4,
    bf16_t* __restrict__ d0, bf16_t* __restrict__ d1, bf16_t* __restrict__ d2,
    bf16_t* __restrict__ d3, bf16_t* __restrict__ d4,
    uint4* __restrict__ mask4)
{
    int which = blockIdx.y;
    int i = blockIdx.x * blockDim.x + threadIdx.x;
    if (which == 5) {
        if (i < Nn * MW / 4) mask4[i] = make_uint4(0, 0, 0, 0);
        return;
    }
    const float* s = (which == 0) ? s0 : (which == 1) ? s1 : (which == 2) ? s2 : (which == 3) ? s3 : s4;
    bf16_t* d = (which == 0) ? d0 : (which == 1) ? d1 : (which == 2) ? d2 : (which == 3) ? d3 : d4;
    int n4 = (which == 0) ? (Bb * Nn * Hh / 4) : (Hh * Hh / 4);
    if (i >= n4) return;
    float4 v = ((const float4*)s)[i];
    bf16x4 o = {(bf16_t)v.x, (bf16_t)v.y, (bf16_t)v.z, (bf16_t)v.w};
    ((bf16x4*)d)[i] = o;
}

// ============ K2: edge scatter (first 256 blocks) + QKV MFMA GEMM ===========
__global__ __launch_bounds__(256) void qkv_gemm_mask_kernel(
    const bf16_t* __restrict__ xb,
    const bf16_t* __restrict__ Wqb, const bf16_t* __restrict__ Wkb, const bf16_t* __restrict__ Wvb,
    float* __restrict__ Qb, bf16_t* __restrict__ Kb16, bf16_t* __restrict__ Vb16,
    const int* __restrict__ ei, unsigned int* __restrict__ mask)
{
    __shared__ bf16_t As[64 * LDA2];
    __shared__ bf16_t Ws[64 * LDA2];
    int t = threadIdx.x;
    int linb = blockIdx.y * 64 + blockIdx.x;    // 0..767
    int gtid = linb * 256 + t;
    if (gtid < NEDGE) {
        int src = ei[gtid], dst = ei[NEDGE + gtid];
        atomicOr(&mask[src * MW + (dst >> 5)], 1u << (dst & 31));
    }
    int lane = t & 63, w = t >> 6;
    int wm = w & 1, wn = w >> 1;
    int ml = lane & 15, quad = lane >> 4;
    int m0 = blockIdx.x * 64;
    int wsel = blockIdx.y >> 2;
    const bf16_t* W = (wsel == 0) ? Wqb : ((wsel == 1) ? Wkb : Wvb);
    int n0 = (blockIdx.y & 3) * 64;
    int srow = t >> 3;
    int scol = (t & 7) * 8;
    f32x4 acc[2][2];
    f32x4 zf = {0.f, 0.f, 0.f, 0.f};
    acc[0][0] = zf; acc[0][1] = zf; acc[1][0] = zf; acc[1][1] = zf;

    for (int k0 = 0; k0 < Hh; k0 += 64) {
        bf16x8 a0 = *(const bf16x8*)(xb + (size_t)(m0 + srow) * Hh + k0 + scol);
        bf16x8 a1 = *(const bf16x8*)(xb + (size_t)(m0 + srow + 32) * Hh + k0 + scol);
        bf16x8 b0 = *(const bf16x8*)(W + (size_t)(n0 + srow) * Hh + k0 + scol);
        bf16x8 b1 = *(const bf16x8*)(W + (size_t)(n0 + srow + 32) * Hh + k0 + scol);
        __syncthreads();
        *(bf16x8*)&As[srow * LDA2 + scol] = a0;
        *(bf16x8*)&As[(srow + 32) * LDA2 + scol] = a1;
        *(bf16x8*)&Ws[srow * LDA2 + scol] = b0;
        *(bf16x8*)&Ws[(srow + 32) * LDA2 + scol] = b1;
        __syncthreads();
        #pragma unroll
        for (int kk = 0; kk < 64; kk += 32) {
            bf16x8 af[2], bfr[2];
            #pragma unroll
            for (int i2 = 0; i2 < 2; ++i2) {
                af[i2]  = *(const bf16x8*)&As[(wm * 32 + i2 * 16 + ml) * LDA2 + kk + quad * 8];
                bfr[i2] = *(const bf16x8*)&Ws[(wn * 32 + i2 * 16 + ml) * LDA2 + kk + quad * 8];
            }
            #pragma unroll
            for (int i2 = 0; i2 < 2; ++i2)
                #pragma unroll
                for (int j2 = 0; j2 < 2; ++j2)
                    acc[i2][j2] = __builtin_amdgcn_mfma_f32_16x16x32_bf16(af[i2], bfr[j2], acc[i2][j2], 0, 0, 0);
        }
    }
    #pragma unroll
    for (int i2 = 0; i2 < 2; ++i2)
        #pragma unroll
        for (int j2 = 0; j2 < 2; ++j2)
            #pragma unroll
            for (int r = 0; r < 4; ++r) {
                int mg = m0 + wm * 32 + i2 * 16 + quad * 4 + r;
                int ng = n0 + wn * 32 + j2 * 16 + ml;
                float v = acc[i2][j2][r];
                if (wsel == 0)      Qb[(size_t)mg * Hh + ng] = v;
                else if (wsel == 1) Kb16[(size_t)mg * Hh + ng] = (bf16_t)v;
                else                Vb16[(size_t)mg * Hh + ng] = (bf16_t)v;
            }
}

// ====== K3: sparse attention (4 rows/block) + out-proj MFMA + LayerNorm =====
struct AttnLds {
    float aout[4][Hh];          // attention rows, consumed by out-proj phase
    unsigned short nbr[Nn];
    float qs[Hh];
    float sraw[64 * 9];
    float scw2[NH * 64];
    float alpha_l[NH];
    float linv_l[NH];
    float obuf[4][Hh];
    int nn_sh;
};
struct OlnLds {
    float aout[4][Hh];          // same offset as AttnLds.aout
    union { bf16_t Ws[64 * 136]; float yb[4][260]; } u2;
};
union FusedLds { AttnLds a; OlnLds o; };

__global__ __launch_bounds__(256) void attn_out_ln_kernel(
    const float* __restrict__ Qb, const bf16_t* __restrict__ Kb16, const bf16_t* __restrict__ Vb16,
    const unsigned int* __restrict__ mask, const bf16_t* __restrict__ Wob,
    const float* __restrict__ x, const float* __restrict__ gamma,
    const float* __restrict__ beta, float* __restrict__ out)
{
    __shared__ FusedLds u;
    int blk = blockIdx.x, t = threadIdx.x;
    int lane = t & 63, w = t >> 6;
    int ml = lane & 15, quad = lane >> 4;
    int h = t >> 5, dl = t & 31;
    int hw = lane >> 3;               // head owning cols 4*lane..4*lane+3
    const float scale = 0.17677669529663687f;  // 1/sqrt(32)

    // ---------------- attention: 4 rows sequentially ----------------
    for (int rr = 0; rr < 4; ++rr) {
        int ri = blk * 4 + rr;
        int b = ri >> 11, i = ri & (Nn - 1);
        __syncthreads();              // LDS reuse guard (prev row)
        if (t < 64) {                 // wave 0: dedup'd neighbor extraction
            unsigned int bits = mask[i * MW + t];
            int cnt = __popc(bits);
            int incl = cnt;
            #pragma unroll
            for (int off = 1; off < 64; off <<= 1) {
                int v = __shfl_up(incl, off, 64);
                if (t >= off) incl += v;
            }
            int idx = incl - cnt;
            unsigned int bb = bits;
            while (bb) {
                int bit = __ffs(bb) - 1;
                u.a.nbr[idx++] = (unsigned short)(t * 32 + bit);
                bb &= bb - 1;
            }
            if (t == 63) u.a.nn_sh = incl;
        }
        u.a.qs[t] = Qb[(size_t)ri * Hh + t];
        __syncthreads();
        int nn = u.a.nn_sh;

        float m_run = -1e30f, l_run = 0.f;
        float o0 = 0.f, o1 = 0.f, o2 = 0.f, o3 = 0.f;
        int nch = (nn + 63) >> 6;
        for (int c = 0; c < nch; ++c) {
            int base = c << 6;
            int lim = min(64, nn - base);
            // scores: wave w rows w, w+4, ..., 60; lane covers cols 4l..4l+3
            float4 qv = *(const float4*)&u.a.qs[lane << 2];
            #pragma unroll
            for (int s = 0; s < 16; ++s) {
                int r = (s << 2) + w;
                if (r < lim) {
                    int j = u.a.nbr[base + r];
                    bf16x4 kv = *(const bf16x4*)(Kb16 + (((size_t)((b << 11) + j)) << 8) + (lane << 2));
                    float p = fmaf((float)kv.x, qv.x, fmaf((float)kv.y, qv.y,
                              fmaf((float)kv.z, qv.z, (float)kv.w * qv.w)));
                    p += __shfl_xor(p, 1, 64);
                    p += __shfl_xor(p, 2, 64);
                    p += __shfl_xor(p, 4, 64);
                    if ((lane & 7) == 0) u.a.sraw[r * 9 + (lane >> 3)] = p * scale;
                }
            }
            __syncthreads();
            // softmax: thread (h,dl) owns chunk neighbors dl and dl+32 of head h
            float s0 = (dl < lim) ? u.a.sraw[dl * 9 + h] : -1e30f;
            float s1 = (dl + 32 < lim) ? u.a.sraw[(dl + 32) * 9 + h] : -1e30f;
            float mc = fmaxf(s0, s1);
            #pragma unroll
            for (int m = 1; m < 32; m <<= 1) mc = fmaxf(mc, __shfl_xor(mc, m, 64));
            float m_new = fmaxf(m_run, mc);
            float w0 = __expf(s0 - m_new), w1 = __expf(s1 - m_new);
            float sum = w0 + w1;
            #pragma unroll
            for (int m = 1; m < 32; m <<= 1) sum += __shfl_xor(sum, m, 64);
            float alpha = __expf(m_run - m_new);
            l_run = l_run * alpha + sum;
            m_run = m_new;
            u.a.scw2[h * 64 + dl] = w0;
            u.a.scw2[h * 64 + dl + 32] = w1;
            if (dl == 0) u.a.alpha_l[h] = alpha;
            __syncthreads();
            // V accumulate: wave w rows w, w+4, ...; thread covers 4 cols
            float av = u.a.alpha_l[hw];
            o0 *= av; o1 *= av; o2 *= av; o3 *= av;
            #pragma unroll
            for (int s = 0; s < 16; ++s) {
                int r = (s << 2) + w;
                if (r < lim) {
                    int j = u.a.nbr[base + r];
                    float wg = u.a.scw2[hw * 64 + r];
                    bf16x4 vv = *(const bf16x4*)(Vb16 + (((size_t)((b << 11) + j)) << 8) + (lane << 2));
                    o0 = fmaf(wg, (float)vv.x, o0);
                    o1 = fmaf(wg, (float)vv.y, o1);
                    o2 = fmaf(wg, (float)vv.z, o2);
                    o3 = fmaf(wg, (float)vv.w, o3);
                }
            }
            __syncthreads();          // sraw/scw2 reused next chunk
        }
        if (dl == 0) u.a.linv_l[h] = (l_run > 0.f) ? 1.f / l_run : 0.f;
        u.a.obuf[w][(lane << 2) + 0] = o0;
        u.a.obuf[w][(lane << 2) + 1] = o1;
        u.a.obuf[w][(lane << 2) + 2] = o2;
        u.a.obuf[w][(lane << 2) + 3] = o3;
        __syncthreads();
        float val = u.a.obuf[0][t] + u.a.obuf[1][t] + u.a.obuf[2][t] + u.a.obuf[3][t];
        u.a.aout[rr][t] = val * u.a.linv_l[t >> 5];
    }
    __syncthreads();

    // ------------- out = LN(aout @ Wo^T + x), MFMA M=16 -------------
    {
        int mlr = ml & 3;             // A rows 4..15 duplicate rows 0..3 (discarded)
        bf16x8 af[8];
        #pragma unroll
        for (int kc = 0; kc < 8; ++kc) {
            float4 a0 = *(const float4*)&u.o.aout[mlr][kc * 32 + quad * 8];
            float4 a1 = *(const float4*)&u.o.aout[mlr][kc * 32 + quad * 8 + 4];
            bf16x8 f = {(bf16_t)a0.x, (bf16_t)a0.y, (bf16_t)a0.z, (bf16_t)a0.w,
                        (bf16_t)a1.x, (bf16_t)a1.y, (bf16_t)a1.z, (bf16_t)a1.w};
            af[kc] = f;
        }
        int wr = t >> 2, wc = (t & 3) * 32;
        f32x4 acc[4];
        f32x4 zf = {0.f, 0.f, 0.f, 0.f};
        acc[0] = zf; acc[1] = zf; acc[2] = zf; acc[3] = zf;
        #pragma unroll
        for (int nc = 0; nc < 4; ++nc) {
            #pragma unroll
            for (int kcp = 0; kcp < 2; ++kcp) {
                bf16x8 wv0 = *(const bf16x8*)(Wob + (size_t)(nc * 64 + wr) * Hh + kcp * 128 + wc);
                bf16x8 wv1 = *(const bf16x8*)(Wob + (size_t)(nc * 64 + wr) * Hh + kcp * 128 + wc + 8);
                bf16x8 wv2 = *(const bf16x8*)(Wob + (size_t)(nc * 64 + wr) * Hh + kcp * 128 + wc + 16);
                bf16x8 wv3 = *(const bf16x8*)(Wob + (size_t)(nc * 64 + wr) * Hh + kcp * 128 + wc + 24);
                __syncthreads();      // previous stage's fragment reads complete
                *(bf16x8*)&u.o.u2.Ws[wr * 136 + wc +  0] = wv0;
                *(bf16x8*)&u.o.u2.Ws[wr * 136 + wc +  8] = wv1;
                *(bf16x8*)&u.o.u2.Ws[wr * 136 + wc + 16] = wv2;
                *(bf16x8*)&u.o.u2.Ws[wr * 136 + wc + 24] = wv3;
                __syncthreads();
                #pragma unroll
                for (int k2 = 0; k2 < 4; ++k2) {
                    bf16x8 bfr = *(const bf16x8*)&u.o.u2.Ws[(w * 16 + ml) * 136 + k2 * 32 + quad * 8];
                    acc[nc] = __builtin_amdgcn_mfma_f32_16x16x32_bf16(af[kcp * 4 + k2], bfr, acc[nc], 0, 0, 0);
                }
            }
        }
        __syncthreads();              // Ws dead -> alias as yb
        if (quad == 0) {
            #pragma unroll
            for (int nc = 0; nc < 4; ++nc)
                #pragma unroll
                for (int r = 0; r < 4; ++r) {
                    int col = nc * 64 + w * 16 + ml;
                    u.o.u2.yb[r][col] = acc[nc][r] + x[(size_t)(blk * 4 + r) * Hh + col];
                }
        }
        __syncthreads();
        // LN: wave w handles row w
        float4 v = *(const float4*)&u.o.u2.yb[w][lane * 4];
        float sum = v.x + v.y + v.z + v.w;
        #pragma unroll
        for (int m = 1; m < 64; m <<= 1) sum += __shfl_xor(sum, m, 64);
        float mu = sum * (1.f / Hh);
        float4 d = {v.x - mu, v.y - mu, v.z - mu, v.w - mu};
        float ss = d.x * d.x + d.y * d.y + d.z * d.z + d.w * d.w;
        #pragma unroll
        for (int m = 1; m < 64; m <<= 1) ss += __shfl_xor(ss, m, 64);
        float r = rsqrtf(ss * (1.f / Hh) + LN_EPS);
        float4 g  = *(const float4*)(gamma + lane * 4);
        float4 bt = *(const float4*)(beta + lane * 4);
        float4 ov = {d.x * r * g.x + bt.x, d.y * r * g.y + bt.y,
                     d.z * r * g.z + bt.z, d.w * r * g.w + bt.w};
        *(float4*)(out + (size_t)(blk * 4 + w) * Hh + lane * 4) = ov;
    }
}

extern "C" void kernel_launch(void* const* d_in, const int* in_sizes, int n_in,
                              void* d_out, int out_size, void* d_ws, size_t ws_size,
                              hipStream_t stream) {
    const float* x     = (const float*)d_in[0];
    const int*   ei    = (const int*)d_in[1];
    // d_in[2] = edge_weights: unused by the reference
    const float* Wq    = (const float*)d_in[3];
    const float* Wk    = (const float*)d_in[4];
    const float* Wv    = (const float*)d_in[5];
    const float* Wo    = (const float*)d_in[6];
    const float* gamma = (const float*)d_in[7];
    const float* beta  = (const float*)d_in[8];
    float* out = (float*)d_out;

    const int NTOK = Bb * Nn * Hh;  // 1048576
    float*  Qb   = (float*)d_ws;
    bf16_t* Kb16 = (bf16_t*)(Qb + NTOK);
    bf16_t* Vb16 = Kb16 + NTOK;
    unsigned int* mask = (unsigned int*)(Vb16 + NTOK);
    bf16_t* xb  = (bf16_t*)(mask + Nn * MW);
    bf16_t* Wqb = xb + NTOK;
    bf16_t* Wkb = Wqb + Hh * Hh;
    bf16_t* Wvb = Wkb + Hh * Hh;
    bf16_t* Wob = Wvb + Hh * Hh;

    hipLaunchKernelGGL(cvt_zero_kernel, dim3(NTOK / 4 / 256, 6), dim3(256), 0, stream,
                       x, Wq, Wk, Wv, Wo, xb, Wqb, Wkb, Wvb, Wob, (uint4*)mask);
    hipLaunchKernelGGL(qkv_gemm_mask_kernel, dim3(64, 12), dim3(256), 0, stream,
                       xb, Wqb, Wkb, Wvb, Qb, Kb16, Vb16, ei, mask);
    hipLaunchKernelGGL(attn_out_ln_kernel, dim3(Bb * Nn / 4), dim3(256), 0, stream,
                       Qb, Kb16, Vb16, mask, Wob, x, gamma, beta, out);
}

// Round 8
// 118.312 us; speedup vs baseline: 1.1695x; 1.1695x over previous
//
#include <hip/hip_runtime.h>
#include <math.h>

#define Bb 2
#define Nn 2048
#define Hh 256
#define NH 8
#define NEDGE 65536
#define LN_EPS 1e-5f
#define MW 64          // mask words per row = N/32
#define LDA2 72

typedef __bf16 bf16_t;
typedef bf16_t bf16x8 __attribute__((ext_vector_type(8)));
typedef bf16_t bf16x4 __attribute__((ext_vector_type(4)));
typedef float f32x4 __attribute__((ext_vector_type(4)));

__device__ __forceinline__ bf16x4 cvt4(float4 v) {
    bf16x4 o = {(bf16_t)v.x, (bf16_t)v.y, (bf16_t)v.z, (bf16_t)v.w};
    return o;
}

// ========== K2: edge scatter + QKV MFMA GEMM (inline fp32->bf16 cvt) ========
__global__ __launch_bounds__(256) void qkv_gemm_mask_kernel(
    const float* __restrict__ x,
    const float* __restrict__ Wq, const float* __restrict__ Wk, const float* __restrict__ Wv,
    float* __restrict__ Qb, bf16_t* __restrict__ Kb16, bf16_t* __restrict__ Vb16,
    const int* __restrict__ ei, unsigned int* __restrict__ mask)
{
    __shared__ bf16_t As[64 * LDA2];
    __shared__ bf16_t Ws[64 * LDA2];
    int t = threadIdx.x;
    int linb = blockIdx.y * 64 + blockIdx.x;    // 0..767
    int gtid = linb * 256 + t;
    if (gtid < NEDGE) {
        int src = ei[gtid], dst = ei[NEDGE + gtid];
        atomicOr(&mask[src * MW + (dst >> 5)], 1u << (dst & 31));
    }
    int lane = t & 63, w = t >> 6;
    int wm = w & 1, wn = w >> 1;
    int ml = lane & 15, quad = lane >> 4;
    int m0 = blockIdx.x * 64;
    int wsel = blockIdx.y >> 2;
    const float* W = (wsel == 0) ? Wq : ((wsel == 1) ? Wk : Wv);
    int n0 = (blockIdx.y & 3) * 64;
    int srow = t >> 4;            // 0..15
    int scol = (t & 15) * 4;      // 0..60
    f32x4 acc[2][2];
    f32x4 zf = {0.f, 0.f, 0.f, 0.f};
    acc[0][0] = zf; acc[0][1] = zf; acc[1][0] = zf; acc[1][1] = zf;

    for (int k0 = 0; k0 < Hh; k0 += 64) {
        float4 av[4], wv4[4];
        #pragma unroll
        for (int u = 0; u < 4; ++u) {
            av[u]  = *(const float4*)(x + (size_t)(m0 + u * 16 + srow) * Hh + k0 + scol);
            wv4[u] = *(const float4*)(W + (size_t)(n0 + u * 16 + srow) * Hh + k0 + scol);
        }
        __syncthreads();
        #pragma unroll
        for (int u = 0; u < 4; ++u) {
            *(bf16x4*)&As[(u * 16 + srow) * LDA2 + scol] = cvt4(av[u]);
            *(bf16x4*)&Ws[(u * 16 + srow) * LDA2 + scol] = cvt4(wv4[u]);
        }
        __syncthreads();
        #pragma unroll
        for (int kk = 0; kk < 64; kk += 32) {
            bf16x8 af[2], bfr[2];
            #pragma unroll
            for (int i2 = 0; i2 < 2; ++i2) {
                af[i2]  = *(const bf16x8*)&As[(wm * 32 + i2 * 16 + ml) * LDA2 + kk + quad * 8];
                bfr[i2] = *(const bf16x8*)&Ws[(wn * 32 + i2 * 16 + ml) * LDA2 + kk + quad * 8];
            }
            #pragma unroll
            for (int i2 = 0; i2 < 2; ++i2)
                #pragma unroll
                for (int j2 = 0; j2 < 2; ++j2)
                    acc[i2][j2] = __builtin_amdgcn_mfma_f32_16x16x32_bf16(af[i2], bfr[j2], acc[i2][j2], 0, 0, 0);
        }
    }
    #pragma unroll
    for (int i2 = 0; i2 < 2; ++i2)
        #pragma unroll
        for (int j2 = 0; j2 < 2; ++j2)
            #pragma unroll
            for (int r = 0; r < 4; ++r) {
                int mg = m0 + wm * 32 + i2 * 16 + quad * 4 + r;
                int ng = n0 + wn * 32 + j2 * 16 + ml;
                float v = acc[i2][j2][r];
                if (wsel == 0)      Qb[(size_t)mg * Hh + ng] = v;
                else if (wsel == 1) Kb16[(size_t)mg * Hh + ng] = (bf16_t)v;
                else                Vb16[(size_t)mg * Hh + ng] = (bf16_t)v;
            }
}

// ====== K3: sparse attention, 1 row/block. Conflict-free sw[r*9+h] layout,
// unconditional clamped K/V loads (weights 0 for padded lanes). ======
__global__ __launch_bounds__(256) void attn6_kernel(
    const float* __restrict__ Qb, const bf16_t* __restrict__ Kb16, const bf16_t* __restrict__ Vb16,
    const unsigned int* __restrict__ mask, float* __restrict__ attnb)
{
    __shared__ unsigned short nbr[Nn];   // 4 KB
    __shared__ float qs[Hh];
    __shared__ float sw[32 * 9];         // raw scores -> weights, [r*9 + h]
    __shared__ float alpha_l[NH];
    __shared__ float linv_l[NH];
    __shared__ float obuf[4][Hh];        // 4 KB
    __shared__ int nn_sh;
    int gid = blockIdx.x;                // == b*Nn + i
    int i = gid & (Nn - 1);
    int t = threadIdx.x;
    int h = t >> 5, dl = t & 31;
    int w = t >> 6, lane = t & 63;
    int hw = lane >> 3;                  // head owning cols 4*lane..4*lane+3
    int kvbase = (gid >> 11) << 11;      // b*Nn

    float qreg = Qb[(size_t)gid * Hh + t];   // issue early
    if (t < 64) {   // wave 0: extract dedup'd neighbor list from bitmask
        unsigned int bits = mask[i * MW + t];
        int cnt = __popc(bits);
        int incl = cnt;
        #pragma unroll
        for (int off = 1; off < 64; off <<= 1) {
            int v = __shfl_up(incl, off, 64);
            if (t >= off) incl += v;
        }
        int idx = incl - cnt;
        unsigned int bb = bits;
        while (bb) {
            int bit = __ffs(bb) - 1;
            nbr[idx++] = (unsigned short)(t * 32 + bit);
            bb &= bb - 1;
        }
        if (t == 63) nn_sh = incl;
    }
    qs[t] = qreg;
    __syncthreads();
    int nn = nn_sh;

    float m_run = -1e30f, l_run = 0.f;
    float o0 = 0.f, o1 = 0.f, o2 = 0.f, o3 = 0.f;
    const float scale = 0.17677669529663687f;  // 1/sqrt(32)
    int nch = (nn + 31) >> 5;
    for (int c = 0; c < nch; ++c) {
        int base = c << 5;
        int lim = min(32, nn - base);
        // ---- scores: wave w rows w,w+4,...; lane covers cols 4l..4l+3 ----
        float4 qv = *(const float4*)&qs[lane << 2];
        #pragma unroll
        for (int s = 0; s < 8; ++s) {
            int r = (s << 2) + w;
            int j = nbr[min(base + r, nn - 1)];          // clamped: always valid
            bf16x4 kv = *(const bf16x4*)(Kb16 + (((size_t)(kvbase + j)) << 8) + (lane << 2));
            float p = fmaf((float)kv.x, qv.x, fmaf((float)kv.y, qv.y,
                      fmaf((float)kv.z, qv.z, (float)kv.w * qv.w)));
            p += __shfl_xor(p, 1, 64);
            p += __shfl_xor(p, 2, 64);
            p += __shfl_xor(p, 4, 64);
            if ((lane & 7) == 0 && r < lim) sw[r * 9 + (lane >> 3)] = p * scale;
        }
        __syncthreads();
        // ---- softmax: thread (h,dl) owns chunk-neighbor dl of head h ----
        float s_val = (dl < lim) ? sw[dl * 9 + h] : -1e30f;
        float mc = s_val;
        #pragma unroll
        for (int m = 1; m < 32; m <<= 1) mc = fmaxf(mc, __shfl_xor(mc, m, 64));
        float m_new = fmaxf(m_run, mc);
        float wgt = __expf(s_val - m_new);    // 0 for padded lanes
        float sum = wgt;
        #pragma unroll
        for (int m = 1; m < 32; m <<= 1) sum += __shfl_xor(sum, m, 64);
        float alpha = __expf(m_run - m_new);
        l_run = l_run * alpha + sum;
        m_run = m_new;
        sw[dl * 9 + h] = wgt;                 // overwrite own slot (all 32 written)
        if (dl == 0) alpha_l[h] = alpha;
        __syncthreads();
        // ---- V accumulate: wave w rows w,w+4,...; thread covers 4 cols ----
        float av = alpha_l[hw];
        o0 *= av; o1 *= av; o2 *= av; o3 *= av;
        #pragma unroll
        for (int s = 0; s < 8; ++s) {
            int r = (s << 2) + w;
            int j = nbr[min(base + r, nn - 1)];
            float wg = sw[r * 9 + hw];        // 0 beyond lim
            bf16x4 vv = *(const bf16x4*)(Vb16 + (((size_t)(kvbase + j)) << 8) + (lane << 2));
            o0 = fmaf(wg, (float)vv.x, o0);
            o1 = fmaf(wg, (float)vv.y, o1);
            o2 = fmaf(wg, (float)vv.z, o2);
            o3 = fmaf(wg, (float)vv.w, o3);
        }
        __syncthreads();                      // sw reused next chunk
    }
    if (dl == 0) linv_l[h] = (l_run > 0.f) ? 1.f / l_run : 0.f;
    float4 ov = {o0, o1, o2, o3};
    *(float4*)&obuf[w][lane << 2] = ov;
    __syncthreads();
    float val = obuf[0][t] + obuf[1][t] + obuf[2][t] + obuf[3][t];
    attnb[((size_t)gid << 8) + t] = val * linv_l[t >> 5];
}

// ====== K4: out = LN(attn @ Wo^T + x), 16 rows/block, inline Wo cvt ========
__global__ __launch_bounds__(256) void out_ln_kernel(
    const float* __restrict__ attnb, const float* __restrict__ Wo,
    const float* __restrict__ x, const float* __restrict__ gamma,
    const float* __restrict__ beta, float* __restrict__ out)
{
    __shared__ bf16_t As[16 * LDA2];
    __shared__ __align__(16) char wbuf[256 * LDA2 * sizeof(bf16_t)];  // 36.9 KB
    bf16_t* Ws = (bf16_t*)wbuf;
    float* yb = (float*)wbuf;          // 16 x 260 fp32, aliased after use
    int t = threadIdx.x;
    int lane = t & 63, w = t >> 6;
    int ml = lane & 15, quad = lane >> 4;
    int m0 = blockIdx.x * 16;
    f32x4 acc[4];
    f32x4 zf = {0.f, 0.f, 0.f, 0.f};
    acc[0] = zf; acc[1] = zf; acc[2] = zf; acc[3] = zf;
    int arow = t >> 4, acol = (t & 15) * 4;
    int wrow = t >> 3, wcol = (t & 7) * 8;

    for (int k0 = 0; k0 < Hh; k0 += 64) {
        float4 av = *(const float4*)(attnb + (size_t)(m0 + arow) * Hh + k0 + acol);
        float4 wa[8], wb[8];
        #pragma unroll
        for (int s = 0; s < 8; ++s) {
            wa[s] = *(const float4*)(Wo + (size_t)(wrow + s * 32) * Hh + k0 + wcol);
            wb[s] = *(const float4*)(Wo + (size_t)(wrow + s * 32) * Hh + k0 + wcol + 4);
        }
        __syncthreads();
        *(bf16x4*)&As[arow * LDA2 + acol] = cvt4(av);
        #pragma unroll
        for (int s = 0; s < 8; ++s) {
            *(bf16x4*)&Ws[(wrow + s * 32) * LDA2 + wcol]     = cvt4(wa[s]);
            *(bf16x4*)&Ws[(wrow + s * 32) * LDA2 + wcol + 4] = cvt4(wb[s]);
        }
        __syncthreads();
        #pragma unroll
        for (int kk = 0; kk < 64; kk += 32) {
            bf16x8 af = *(const bf16x8*)&As[ml * LDA2 + kk + quad * 8];
            #pragma unroll
            for (int ct = 0; ct < 4; ++ct) {
                bf16x8 bfr = *(const bf16x8*)&Ws[(w * 64 + ct * 16 + ml) * LDA2 + kk + quad * 8];
                acc[ct] = __builtin_amdgcn_mfma_f32_16x16x32_bf16(af, bfr, acc[ct], 0, 0, 0);
            }
        }
    }
    __syncthreads();   // all Ws reads done before aliasing as yb
    #pragma unroll
    for (int ct = 0; ct < 4; ++ct)
        #pragma unroll
        for (int r = 0; r < 4; ++r) {
            int row = quad * 4 + r;
            int col = w * 64 + ct * 16 + ml;
            yb[row * 260 + col] = acc[ct][r] + x[(size_t)(m0 + row) * Hh + col];
        }
    __syncthreads();
    for (int rr = 0; rr < 4; ++rr) {
        int row = w * 4 + rr;
        float4 v = *(const float4*)&yb[row * 260 + lane * 4];
        float sum = v.x + v.y + v.z + v.w;
        #pragma unroll
        for (int m = 1; m < 64; m <<= 1) sum += __shfl_xor(sum, m, 64);
        float mu = sum * (1.f / Hh);
        float4 d = {v.x - mu, v.y - mu, v.z - mu, v.w - mu};
        float ss = d.x * d.x + d.y * d.y + d.z * d.z + d.w * d.w;
        #pragma unroll
        for (int m = 1; m < 64; m <<= 1) ss += __shfl_xor(ss, m, 64);
        float r = rsqrtf(ss * (1.f / Hh) + LN_EPS);
        float4 g  = *(const float4*)(gamma + lane * 4);
        float4 bt = *(const float4*)(beta + lane * 4);
        float4 ov = {d.x * r * g.x + bt.x, d.y * r * g.y + bt.y,
                     d.z * r * g.z + bt.z, d.w * r * g.w + bt.w};
        *(float4*)(out + (size_t)(m0 + row) * Hh + lane * 4) = ov;
    }
}

extern "C" void kernel_launch(void* const* d_in, const int* in_sizes, int n_in,
                              void* d_out, int out_size, void* d_ws, size_t ws_size,
                              hipStream_t stream) {
    const float* x     = (const float*)d_in[0];
    const int*   ei    = (const int*)d_in[1];
    // d_in[2] = edge_weights: unused by the reference
    const float* Wq    = (const float*)d_in[3];
    const float* Wk    = (const float*)d_in[4];
    const float* Wv    = (const float*)d_in[5];
    const float* Wo    = (const float*)d_in[6];
    const float* gamma = (const float*)d_in[7];
    const float* beta  = (const float*)d_in[8];
    float* out = (float*)d_out;

    const int NTOK = Bb * Nn * Hh;  // 1048576
    float*  Qb    = (float*)d_ws;
    bf16_t* Kb16  = (bf16_t*)(Qb + NTOK);
    bf16_t* Vb16  = Kb16 + NTOK;
    float*  attnb = (float*)(Vb16 + NTOK);
    unsigned int* mask = (unsigned int*)(attnb + NTOK);

    hipMemsetAsync(mask, 0, Nn * MW * sizeof(unsigned int), stream);
    hipLaunchKernelGGL(qkv_gemm_mask_kernel, dim3(64, 12), dim3(256), 0, stream,
                       x, Wq, Wk, Wv, Qb, Kb16, Vb16, ei, mask);
    hipLaunchKernelGGL(attn6_kernel, dim3(Bb * Nn), dim3(256), 0, stream,
                       Qb, Kb16, Vb16, mask, attnb);
    hipLaunchKernelGGL(out_ln_kernel, dim3((Bb * Nn) / 16), dim3(256), 0, stream,
                       attnb, Wo, x, gamma, beta, out);
}